// Round 10
// baseline (299.526 us; speedup 1.0000x reference)
//
#include <hip/hip_runtime.h>
#include <hip/hip_bf16.h>

#define NNODES 100000
#define NEDGES 1600000
#define INC 128
#define HIDC 64
#define BSHIFT 8                      // 256 nodes per bucket
#define NB ((NNODES + 255) / 256)     // 391 buckets
#define TILE 8192                     // edges per fill1 workgroup (32/thread)
#define HSLOTS 8192                   // LDS hash slots in fill2 (32 KB)
#define CAP 8192                      // staging words per bucket (avg load ~4092)
#define NBLK_FILL ((NEDGES + TILE - 1) / TILE)   // 196
#define NBLK_LIN ((NNODES + 63) / 64)            // 1563

__device__ __forceinline__ float bf2f(unsigned int h) {
    return __uint_as_float(h << 16);
}

// ---- fat kernel: fill1 binning (blocks [0, NBLK_FILL)) + lin1 GEMM (rest) ----
// fill1 blocks are FIRST so they co-reside with lin blocks (overlap, no tail).
// lin: out[64-node tile, 64 ch] = x @ w1 + b1, written bf16; software-pipelined.
//      Block NBLK_FILL also computes w44 = w2_lin @ [wc_p|wc_q], bias4.
__global__ __launch_bounds__(256) void fat_kernel(
        const float* __restrict__ x, const float* __restrict__ w,
        const float* __restrict__ b, unsigned short* __restrict__ out,
        const float* __restrict__ w2_lin, const float* __restrict__ b2,
        const float* __restrict__ wc, float* __restrict__ w44,
        float* __restrict__ bias4,
        const int* __restrict__ src, const int* __restrict__ dst,
        int* __restrict__ bucket_fill, unsigned int* __restrict__ staging) {
    __shared__ float xs[64][INC + 4];   // 33.8 KB; fill1 aliases the front
    int t = threadIdx.x;
    if (blockIdx.x < NBLK_FILL) {
        // ---------------- fill1 branch ----------------
        int* cnt = (int*)&xs[0][0];
        int* basepos = cnt + NB;
        for (int i = t; i < NB; i += 256) cnt[i] = 0;
        __syncthreads();
        int tile0 = blockIdx.x * TILE;
        unsigned int sv[32];
        int meta[32];
#pragma unroll
        for (int i = 0; i < 32; i++) {
            int e = tile0 + i * 256 + t;
            meta[i] = -1;
            sv[i] = 0;
            if (e < NEDGES) {
                int s = src[e], d = dst[e];
                int bkt = d >> BSHIFT;
                int r = atomicAdd(&cnt[bkt], 1);     // < TILE = 8192 (13 bits)
                meta[i] = (bkt << 13) | r;
                sv[i] = ((unsigned)(d & 255) << 17) | (unsigned)s;
            }
        }
        __syncthreads();
        for (int i = t; i < NB; i += 256) {
            int c = cnt[i];
            int g = (c > 0) ? atomicAdd(&bucket_fill[i], c) : 0;
            basepos[i] = (i << 13) + g;              // bucket region = [i*CAP, ...)
        }
        __syncthreads();
#pragma unroll
        for (int i = 0; i < 32; i++) {
            if (meta[i] >= 0) {
                int bkt = meta[i] >> 13, r = meta[i] & 8191;
                staging[basepos[bkt] + r] = sv[i];
            }
        }
    } else {
        // ---------------- lin branch ----------------
        int node0 = (blockIdx.x - NBLK_FILL) * 64;
        int nn = min(64, NNODES - node0);
        constexpr int C4 = INC / 4;
        for (int idx = t; idx < 64 * C4; idx += 256) {
            int row = idx / C4, c4 = idx % C4;
            float4 v = make_float4(0.f, 0.f, 0.f, 0.f);
            if (row < nn) v = *(const float4*)(x + (size_t)(node0 + row) * INC + c4 * 4);
            *(float4*)(&xs[row][c4 * 4]) = v;
        }
        __syncthreads();
        int tn = t >> 4, tc = t & 15;
        int n0 = tn * 4, c0 = tc * 4;
        float4 bb = *(const float4*)(b + c0);
        float acc[4][4];
#pragma unroll
        for (int i = 0; i < 4; i++) {
            acc[i][0] = bb.x; acc[i][1] = bb.y; acc[i][2] = bb.z; acc[i][3] = bb.w;
        }
        float xr[4][4], wr[4][4], xn[4][4], wn[4][4];
#pragma unroll
        for (int i = 0; i < 4; i++)
            *(float4*)&xr[i][0] = *(const float4*)(&xs[n0 + i][0]);
#pragma unroll
        for (int j = 0; j < 4; j++)
            *(float4*)&wr[j][0] = *(const float4*)(w + (size_t)j * 64 + c0);
#pragma unroll 2
        for (int k = 0; k < INC; k += 4) {
            int kn = (k + 4 < INC) ? (k + 4) : 0;    // wrap: harmless dead prefetch
#pragma unroll
            for (int i = 0; i < 4; i++)
                *(float4*)&xn[i][0] = *(const float4*)(&xs[n0 + i][kn]);
#pragma unroll
            for (int j = 0; j < 4; j++)
                *(float4*)&wn[j][0] = *(const float4*)(w + (size_t)(kn + j) * 64 + c0);
#pragma unroll
            for (int i = 0; i < 4; i++)
#pragma unroll
                for (int kk = 0; kk < 4; kk++)
#pragma unroll
                    for (int j = 0; j < 4; j++)
                        acc[i][j] += xr[i][kk] * wr[kk][j];
#pragma unroll
            for (int i = 0; i < 4; i++)
#pragma unroll
                for (int kk = 0; kk < 4; kk++) {
                    xr[i][kk] = xn[i][kk];
                    wr[i][kk] = wn[i][kk];
                }
        }
#pragma unroll
        for (int i = 0; i < 4; i++) {
            int node = node0 + n0 + i;
            if (node < NNODES) {
                __hip_bfloat16 h0 = __float2bfloat16(acc[i][0]);
                __hip_bfloat16 h1 = __float2bfloat16(acc[i][1]);
                __hip_bfloat16 h2 = __float2bfloat16(acc[i][2]);
                __hip_bfloat16 h3 = __float2bfloat16(acc[i][3]);
                ushort4 pk = make_ushort4(*(unsigned short*)&h0, *(unsigned short*)&h1,
                                          *(unsigned short*)&h2, *(unsigned short*)&h3);
                *(ushort4*)(out + (size_t)node * 64 + c0) = pk;
            }
        }
        if (blockIdx.x == NBLK_FILL) {
            int k = t >> 2, j = t & 3;
            float a = 0.0f;
#pragma unroll 8
            for (int i = 0; i < 64; i++) {
                float w4 = (j < 2) ? wc[i * 2 + j] : wc[(64 + i) * 2 + (j - 2)];
                a += w2_lin[k * 64 + i] * w4;
            }
            w44[k * 4 + j] = a;
            if (k == 0) {
                float bb4 = 0.0f;
                for (int i = 0; i < 64; i++) {
                    float w4 = (j < 2) ? wc[i * 2 + j] : wc[(64 + i) * 2 + (j - 2)];
                    bb4 += b2[i] * w4;
                }
                bias4[j] = bb4;
            }
        }
    }
}

// fill pass 2: one WG per 256-node bucket (~52 KB LDS -> 3 blocks/CU).
// Phase A: per-node counts (+rank in LDS), per-(node,src) dedup via LDS hash.
// In-block scans -> global row_off + norm. Phase B: scatter csr (L2-hot).
__global__ __launch_bounds__(256) void fill2_kernel(
        const int* __restrict__ bucket_fill, const unsigned int* __restrict__ staging,
        int* __restrict__ csr_src, int* __restrict__ row_off,
        float* __restrict__ norm, int n_nodes) {
    __shared__ int cnt[256];
    __shared__ int dcount[256];
    __shared__ int off[257];
    __shared__ int pscan[256];
    __shared__ unsigned short rank16[CAP];   // 16 KB
    __shared__ unsigned int ht[HSLOTS];      // 32 KB (front 2 KB aliased as bpre)
    __shared__ int s_base, s_total;
    int t = threadIdx.x;
    int b = blockIdx.x;
    int node0 = b << BSHIFT;
    int nn = min(256, n_nodes - node0);
    cnt[t] = 0; dcount[t] = 0;
    // --- bucket-base scan (bpre aliases ht; ht init comes after) ---
    int* bpre = (int*)ht;
    int a0 = (2 * t < NB) ? bucket_fill[2 * t] : 0;
    int a1 = (2 * t + 1 < NB) ? bucket_fill[2 * t + 1] : 0;
    pscan[t] = a0 + a1;
    __syncthreads();
    for (int o = 1; o < 256; o <<= 1) {
        int xx = (t >= o) ? pscan[t - o] : 0;
        __syncthreads();
        pscan[t] += xx;
        __syncthreads();
    }
    int excl = pscan[t] - (a0 + a1);
    bpre[2 * t] = excl;
    bpre[2 * t + 1] = excl + a0;
    __syncthreads();
    if (t == 0) { s_base = bpre[b]; s_total = bucket_fill[b]; }
    __syncthreads();
    {   // hash sentinel init (overwrites bpre)
        uint4* h4 = (uint4*)ht;
        uint4 ff = make_uint4(0xFFFFFFFFu, 0xFFFFFFFFu, 0xFFFFFFFFu, 0xFFFFFFFFu);
        for (int i = t; i < HSLOTS / 4; i += 256) h4[i] = ff;
    }
    __syncthreads();
    int start = b << 13;
    int total = s_total;
    // phase A: count + rank + dedup
    for (int li = t; li < total; li += 256) {
        unsigned int w = staging[start + li];
        int s = (int)(w & 0x1FFFFu);
        int dl = (int)(w >> 17);
        int r = atomicAdd(&cnt[dl], 1);
        rank16[li] = (unsigned short)r;
        if (s != node0 + dl) {  // self-loops merge with the I-diagonal
            unsigned int slot = ((w * 2654435761u) >> 13) & (HSLOTS - 1);
            while (true) {
                unsigned int prev = atomicCAS(&ht[slot], 0xFFFFFFFFu, w);
                if (prev == 0xFFFFFFFFu) { atomicAdd(&dcount[dl], 1); break; }
                if (prev == w) break;
                slot = (slot + 1) & (HSLOTS - 1);
            }
        }
    }
    __syncthreads();
    // per-node exclusive prefix -> global row offsets
    int cv = cnt[t];
    pscan[t] = cv;
    __syncthreads();
    for (int o = 1; o < 256; o <<= 1) {
        int xx = (t >= o) ? pscan[t - o] : 0;
        __syncthreads();
        pscan[t] += xx;
        __syncthreads();
    }
    off[t] = s_base + pscan[t] - cv;
    if (t == 255) off[256] = s_base + pscan[255];
    __syncthreads();
    if (t < nn) {
        row_off[node0 + t] = off[t];
        norm[node0 + t] = 1.0f / (1.0f + (float)dcount[t]);
    }
    if (t == 0 && b == NB - 1) row_off[n_nodes] = off[nn];
    // phase B: scatter csr (contiguous bucket region, single-WG-owned)
    for (int li = t; li < total; li += 256) {
        unsigned int w = staging[start + li];
        int s = (int)(w & 0x1FFFFu);
        int dl = (int)(w >> 17);
        csr_src[off[dl] + (int)rank16[li]] = s;
    }
}

// Two nodes per wave: lanes 0-31 = node A, 32-63 = node B; each lane owns two
// channels (one bf16x2 dword). CSR gather-sum + PAN combine + relu + rank-4
// projection (u = h1 @ w44 + bias4). h1 never hits global memory.
__global__ void agg_h_kernel(const unsigned int* __restrict__ lin32,
                             const int* __restrict__ row_off,
                             const int* __restrict__ csr_src, const float* __restrict__ norm,
                             const float* __restrict__ wpan, const float* __restrict__ w44,
                             const float* __restrict__ bias4, float* __restrict__ u,
                             int n_nodes) {
    int t = threadIdx.x;
    int wv = t >> 6;
    int lane = t & 63;
    int half = lane >> 5;
    int sl = lane & 31;
    int node = blockIdx.x * 8 + wv * 2 + half;
    bool vn = node < n_nodes;
    int e0 = 0, d = 0;
    if (vn) {
        e0 = row_off[node];
        d = row_off[node + 1] - e0;
    }
    int dmax = max(d, __shfl_xor(d, 32));
    float accLo = 0.0f, accHi = 0.0f;
    for (int base = 0; base < dmax; base += 8) {
#pragma unroll
        for (int k = 0; k < 8; k++) {
            int idx = base + k;
            bool v = idx < d;
            int s = 0;
            if (v) s = csr_src[e0 + idx];
            unsigned int wd = lin32[s * 32 + sl];
            if (v) {
                accLo += bf2f(wd & 0xFFFFu);
                accHi += bf2f(wd >> 16);
            }
        }
    }
    float w0 = wpan[0];
    float w01 = wpan[0] * wpan[1];
    unsigned int wself = vn ? lin32[node * 32 + sl] : 0u;
    float nr = vn ? norm[node] : 0.0f;
    float vLo = fmaxf(nr * (w0 * bf2f(wself & 0xFFFFu) + w01 * accLo), 0.0f);
    float vHi = fmaxf(nr * (w0 * bf2f(wself >> 16) + w01 * accHi), 0.0f);
    int c0 = 2 * sl;
    float4 wv0 = *(const float4*)(w44 + c0 * 4);
    float4 wv1 = *(const float4*)(w44 + (c0 + 1) * 4);
    float a0 = vLo * wv0.x + vHi * wv1.x;
    float a1 = vLo * wv0.y + vHi * wv1.y;
    float a2 = vLo * wv0.z + vHi * wv1.z;
    float a3 = vLo * wv0.w + vHi * wv1.w;
    for (int off = 16; off; off >>= 1) {
        a0 += __shfl_xor(a0, off);
        a1 += __shfl_xor(a1, off);
        a2 += __shfl_xor(a2, off);
        a3 += __shfl_xor(a3, off);
    }
    if (sl == 0 && vn) {
        float4 bb = *(const float4*)bias4;
        *(float4*)(u + node * 4) =
            make_float4(a0 + bb.x, a1 + bb.y, a2 + bb.z, a3 + bb.w);
    }
}

// Layer-2 aggregate on the rank-4 table: pq[n,j] = norm*(w0*u[n,j] + w01*sum u[src,j]).
__global__ void agg_pq4_kernel(const float* __restrict__ u, const int* __restrict__ row_off,
                               const int* __restrict__ csr_src, const float* __restrict__ norm,
                               const float* __restrict__ wpan, float* __restrict__ pq,
                               int n_nodes) {
    int t = threadIdx.x;
    int node = blockIdx.x * 64 + (t >> 2);
    int j = t & 3;
    if (node >= n_nodes) return;
    int e0 = row_off[node], e1 = row_off[node + 1];
    float acc = 0.0f;
    int e = e0;
    for (; e + 4 <= e1; e += 4) {
        int s0 = csr_src[e + 0], s1 = csr_src[e + 1];
        int s2 = csr_src[e + 2], s3 = csr_src[e + 3];
        float v0 = u[s0 * 4 + j], v1 = u[s1 * 4 + j];
        float v2 = u[s2 * 4 + j], v3 = u[s3 * 4 + j];
        acc += (v0 + v1) + (v2 + v3);
    }
    for (; e < e1; e++) acc += u[csr_src[e] * 4 + j];
    float w0 = wpan[0];
    float w01 = wpan[0] * wpan[1];
    pq[node * 4 + j] = norm[node] * (w0 * u[node * 4 + j] + w01 * acc);
}

__global__ void edge_out_kernel(const int* __restrict__ src, const int* __restrict__ dst,
                                const float* __restrict__ pq, const float* __restrict__ bc,
                                float* __restrict__ out, int n_edges) {
    int e = blockIdx.x * blockDim.x + threadIdx.x;
    if (e >= n_edges) return;
    int r = src[e], c = dst[e];
    float2 p = *(const float2*)(pq + r * 4);
    float2 q = *(const float2*)(pq + c * 4 + 2);
    float2 o = make_float2(p.x + q.x + bc[0], p.y + q.y + bc[1]);
    *(float2*)(out + e * 2) = o;
}

extern "C" void kernel_launch(void* const* d_in, const int* in_sizes, int n_in,
                              void* d_out, int out_size, void* d_ws, size_t ws_size,
                              hipStream_t stream) {
    const float* x      = (const float*)d_in[0];
    const int*   eidx   = (const int*)d_in[1];
    const float* w1_lin = (const float*)d_in[2];
    const float* b1_lin = (const float*)d_in[3];
    const float* w1_pan = (const float*)d_in[4];
    const float* w2_lin = (const float*)d_in[5];
    const float* b2_lin = (const float*)d_in[6];
    const float* w2_pan = (const float*)d_in[7];
    const float* wc     = (const float*)d_in[8];
    const float* bc     = (const float*)d_in[9];
    float* out = (float*)d_out;

    const int* src = eidx;           // edge_index[0]
    const int* dst = eidx + NEDGES;  // edge_index[1]

    // ---- workspace carve-up (all 256B-aligned) ----
    char* ws = (char*)d_ws;
    size_t off = 0;
    auto carve = [&](size_t bytes) {
        char* p = ws + off;
        off = (off + bytes + 255) & ~(size_t)255;
        return p;
    };
    int*   bucket_fill = (int*)carve((size_t)NB * 4);
    int*   row_off  = (int*)carve((size_t)(NNODES + 1) * 4);
    unsigned int* staging = (unsigned int*)carve((size_t)NB * CAP * 4);  // 12.8 MB
    int*   csr_src  = (int*)carve((size_t)NEDGES * 4);
    float* nrm      = (float*)carve((size_t)NNODES * 4);
    unsigned short* bufA = (unsigned short*)carve((size_t)NNODES * HIDC * 2); // lin1 bf16
    float* u        = (float*)carve((size_t)NNODES * 4 * 4);     // rank-4 table
    float* pq       = (float*)carve((size_t)NNODES * 4 * 4);
    float* w44      = (float*)carve((size_t)64 * 4 * 4);
    float* bias4    = (float*)carve((size_t)4 * 4);
    (void)ws_size; (void)in_sizes; (void)n_in; (void)out_size;

    hipMemsetAsync(bucket_fill, 0, (size_t)NB * 4, stream);

    // fat kernel: edge binning (first 196 blocks) || layer-1 GEMM (+ w44)
    fat_kernel<<<NBLK_FILL + NBLK_LIN, 256, 0, stream>>>(
        x, w1_lin, b1_lin, bufA, w2_lin, b2_lin, wc, w44, bias4,
        src, dst, bucket_fill, staging);

    // CSR build pass 2: row_off + dedup + norm + csr scatter
    fill2_kernel<<<NB, 256, 0, stream>>>(bucket_fill, staging, csr_src, row_off, nrm, NNODES);

    // layer 1 aggregate+relu fused with rank-4 projection -> u (2 nodes/wave)
    agg_h_kernel<<<(NNODES + 7) / 8, 256, 0, stream>>>(
        (const unsigned int*)bufA, row_off, csr_src, nrm, w1_pan, w44, bias4, u, NNODES);

    // layer 2 aggregate on the rank-4 table
    agg_pq4_kernel<<<(NNODES + 63) / 64, 256, 0, stream>>>(u, row_off, csr_src, nrm, w2_pan,
                                                           pq, NNODES);

    // edge head: out[e] = p[src[e]] + q[dst[e]] + bc
    edge_out_kernel<<<NEDGES / 256, 256, 0, stream>>>(src, dst, pq, bc, out, NEDGES);
}

// Round 11
// 260.897 us; speedup vs baseline: 1.1481x; 1.1481x over previous
//
#include <hip/hip_runtime.h>
#include <hip/hip_bf16.h>

#define NNODES 100000
#define NEDGES 1600000
#define INC 128
#define HIDC 64
#define BSHIFT 8                      // 256 nodes per bucket
#define NB ((NNODES + 255) / 256)     // 391 buckets
#define TILE 8192                     // edges per fill1 workgroup (32/thread)
#define HSLOTS 8192                   // LDS hash slots in fill2 (32 KB)
#define CAP 8192                      // staging words per bucket (avg load ~4092)
#define CAPE 12288                    // csr words per bucket (padded rows)
#define NBLK_FILL ((NEDGES + TILE - 1) / TILE)   // 196
#define NBLK_LIN ((NNODES + 63) / 64)            // 1563

__device__ __forceinline__ float bf2f(unsigned short h) {
    return __uint_as_float((unsigned)h << 16);
}

// ---- fat kernel: fill1 binning (blocks [0, NBLK_FILL)) + lin1 GEMM (rest) ----
// fill1 blocks FIRST so they co-reside with lin blocks. lin: bf16 out,
// software-pipelined, LDS stride 140 (2-way-free banks). Block NBLK_FILL also
// computes w44/bias4 and zeros the sentinel row bufA[NNODES].
__global__ __launch_bounds__(256) void fat_kernel(
        const float* __restrict__ x, const float* __restrict__ w,
        const float* __restrict__ b, unsigned short* __restrict__ out,
        const float* __restrict__ w2_lin, const float* __restrict__ b2,
        const float* __restrict__ wc, float* __restrict__ w44,
        float* __restrict__ bias4,
        const int* __restrict__ src, const int* __restrict__ dst,
        int* __restrict__ bucket_fill, unsigned int* __restrict__ staging) {
    __shared__ float xs[64][INC + 12];   // stride 140: tn-stride 16 banks -> 2-way (free)
    int t = threadIdx.x;
    if (blockIdx.x < NBLK_FILL) {
        // ---------------- fill1 branch ----------------
        int* cnt = (int*)&xs[0][0];
        int* basepos = cnt + NB;
        for (int i = t; i < NB; i += 256) cnt[i] = 0;
        __syncthreads();
        int tile0 = blockIdx.x * TILE;
        unsigned int sv[32];
        int meta[32];
#pragma unroll
        for (int i = 0; i < 32; i++) {
            int e = tile0 + i * 256 + t;
            meta[i] = -1;
            sv[i] = 0;
            if (e < NEDGES) {
                int s = src[e], d = dst[e];
                int bkt = d >> BSHIFT;
                int r = atomicAdd(&cnt[bkt], 1);     // < TILE = 8192 (13 bits)
                meta[i] = (bkt << 13) | r;
                sv[i] = ((unsigned)(d & 255) << 17) | (unsigned)s;
            }
        }
        __syncthreads();
        for (int i = t; i < NB; i += 256) {
            int c = cnt[i];
            int g = (c > 0) ? atomicAdd(&bucket_fill[i], c) : 0;
            basepos[i] = (i << 13) + g;              // staging region = [i*CAP, ...)
        }
        __syncthreads();
#pragma unroll
        for (int i = 0; i < 32; i++) {
            if (meta[i] >= 0) {
                int bkt = meta[i] >> 13, r = meta[i] & 8191;
                staging[basepos[bkt] + r] = sv[i];
            }
        }
    } else {
        // ---------------- lin branch ----------------
        int node0 = (blockIdx.x - NBLK_FILL) * 64;
        int nn = min(64, NNODES - node0);
        constexpr int C4 = INC / 4;
        for (int idx = t; idx < 64 * C4; idx += 256) {
            int row = idx / C4, c4 = idx % C4;
            float4 v = make_float4(0.f, 0.f, 0.f, 0.f);
            if (row < nn) v = *(const float4*)(x + (size_t)(node0 + row) * INC + c4 * 4);
            *(float4*)(&xs[row][c4 * 4]) = v;
        }
        __syncthreads();
        int tn = t >> 4, tc = t & 15;
        int n0 = tn * 4, c0 = tc * 4;
        float4 bb = *(const float4*)(b + c0);
        float acc[4][4];
#pragma unroll
        for (int i = 0; i < 4; i++) {
            acc[i][0] = bb.x; acc[i][1] = bb.y; acc[i][2] = bb.z; acc[i][3] = bb.w;
        }
        float xr[4][4], wr[4][4], xn[4][4], wn[4][4];
#pragma unroll
        for (int i = 0; i < 4; i++)
            *(float4*)&xr[i][0] = *(const float4*)(&xs[n0 + i][0]);
#pragma unroll
        for (int j = 0; j < 4; j++)
            *(float4*)&wr[j][0] = *(const float4*)(w + (size_t)j * 64 + c0);
#pragma unroll 2
        for (int k = 0; k < INC; k += 4) {
            int kn = (k + 4 < INC) ? (k + 4) : 0;    // wrap: harmless dead prefetch
#pragma unroll
            for (int i = 0; i < 4; i++)
                *(float4*)&xn[i][0] = *(const float4*)(&xs[n0 + i][kn]);
#pragma unroll
            for (int j = 0; j < 4; j++)
                *(float4*)&wn[j][0] = *(const float4*)(w + (size_t)(kn + j) * 64 + c0);
#pragma unroll
            for (int i = 0; i < 4; i++)
#pragma unroll
                for (int kk = 0; kk < 4; kk++)
#pragma unroll
                    for (int j = 0; j < 4; j++)
                        acc[i][j] += xr[i][kk] * wr[kk][j];
#pragma unroll
            for (int i = 0; i < 4; i++)
#pragma unroll
                for (int kk = 0; kk < 4; kk++) {
                    xr[i][kk] = xn[i][kk];
                    wr[i][kk] = wn[i][kk];
                }
        }
#pragma unroll
        for (int i = 0; i < 4; i++) {
            int node = node0 + n0 + i;
            if (node < NNODES) {
                __hip_bfloat16 h0 = __float2bfloat16(acc[i][0]);
                __hip_bfloat16 h1 = __float2bfloat16(acc[i][1]);
                __hip_bfloat16 h2 = __float2bfloat16(acc[i][2]);
                __hip_bfloat16 h3 = __float2bfloat16(acc[i][3]);
                ushort4 pk = make_ushort4(*(unsigned short*)&h0, *(unsigned short*)&h1,
                                          *(unsigned short*)&h2, *(unsigned short*)&h3);
                *(ushort4*)(out + (size_t)node * 64 + c0) = pk;
            }
        }
        if (blockIdx.x == NBLK_FILL) {
            if (t < 16)   // zero sentinel row for padded gathers
                *(ushort4*)(out + (size_t)NNODES * 64 + t * 4) = make_ushort4(0, 0, 0, 0);
            int k = t >> 2, j = t & 3;
            float a = 0.0f;
#pragma unroll 8
            for (int i = 0; i < 64; i++) {
                float w4 = (j < 2) ? wc[i * 2 + j] : wc[(64 + i) * 2 + (j - 2)];
                a += w2_lin[k * 64 + i] * w4;
            }
            w44[k * 4 + j] = a;
            if (k == 0) {
                float bb4 = 0.0f;
                for (int i = 0; i < 64; i++) {
                    float w4 = (j < 2) ? wc[i * 2 + j] : wc[(64 + i) * 2 + (j - 2)];
                    bb4 += b2[i] * w4;
                }
                bias4[j] = bb4;
            }
        }
    }
}

// fill pass 2: one WG per 256-node bucket, fixed csr region [b*CAPE, ...).
// Phase A: per-node counts (+rank in LDS), per-(node,src) dedup via LDS hash.
// Local padded prefix -> row_start/row_pdeg + norm; sentinel-pad rows to x16.
// Phase B: scatter csr (L2-hot re-read, single-WG-owned contiguous writes).
__global__ __launch_bounds__(256) void fill2_kernel(
        const int* __restrict__ bucket_fill, const unsigned int* __restrict__ staging,
        int* __restrict__ csr_src, int* __restrict__ row_start,
        int* __restrict__ row_pdeg, float* __restrict__ norm, int n_nodes) {
    __shared__ int cnt[256];
    __shared__ int dcount[256];
    __shared__ int off[256];
    __shared__ int pscan[256];
    __shared__ unsigned short rank16[CAP];   // 16 KB
    __shared__ unsigned int ht[HSLOTS];      // 32 KB
    int t = threadIdx.x;
    int b = blockIdx.x;
    int node0 = b << BSHIFT;
    int nn = min(256, n_nodes - node0);
    cnt[t] = 0; dcount[t] = 0;
    {
        uint4* h4 = (uint4*)ht;
        uint4 ff = make_uint4(0xFFFFFFFFu, 0xFFFFFFFFu, 0xFFFFFFFFu, 0xFFFFFFFFu);
        for (int i = t; i < HSLOTS / 4; i += 256) h4[i] = ff;
    }
    __syncthreads();
    int start = b << 13;
    int total = bucket_fill[b];
    // phase A: count + rank + dedup
    for (int li = t; li < total; li += 256) {
        unsigned int w = staging[start + li];
        int s = (int)(w & 0x1FFFFu);
        int dl = (int)(w >> 17);
        int r = atomicAdd(&cnt[dl], 1);
        rank16[li] = (unsigned short)r;
        if (s != node0 + dl) {  // self-loops merge with the I-diagonal
            unsigned int slot = ((w * 2654435761u) >> 13) & (HSLOTS - 1);
            while (true) {
                unsigned int prev = atomicCAS(&ht[slot], 0xFFFFFFFFu, w);
                if (prev == 0xFFFFFFFFu) { atomicAdd(&dcount[dl], 1); break; }
                if (prev == w) break;
                slot = (slot + 1) & (HSLOTS - 1);
            }
        }
    }
    __syncthreads();
    // exclusive prefix of padded counts -> csr offsets within [b*CAPE, ...)
    int cv = cnt[t];
    int pv = (cv + 15) & ~15;
    pscan[t] = pv;
    __syncthreads();
    for (int o = 1; o < 256; o <<= 1) {
        int xx = (t >= o) ? pscan[t - o] : 0;
        __syncthreads();
        pscan[t] += xx;
        __syncthreads();
    }
    off[t] = b * CAPE + pscan[t] - pv;
    __syncthreads();
    if (t < nn) {
        row_start[node0 + t] = off[t];
        row_pdeg[node0 + t] = pv;
        norm[node0 + t] = 1.0f / (1.0f + (float)dcount[t]);
    }
    // sentinel-pad the tail of each row
    for (int k = cv; k < pv; k++) csr_src[off[t] + k] = n_nodes;
    // phase B: scatter csr
    for (int li = t; li < total; li += 256) {
        unsigned int w = staging[start + li];
        int s = (int)(w & 0x1FFFFu);
        int dl = (int)(w >> 17);
        csr_src[off[dl] + (int)rank16[li]] = s;
    }
}

// One wave per node (lane = channel). Padded rows: branch-free 16-deep batches;
// 64 row indices fetched by one wave-wide load, broadcast per edge via __shfl.
// Fused: PAN combine + relu + rank-4 projection -> u. h1 never hits global.
__global__ void agg_h_kernel(const unsigned short* __restrict__ lin,
                             const int* __restrict__ row_start,
                             const int* __restrict__ row_pdeg,
                             const int* __restrict__ csr_src,
                             const float* __restrict__ norm,
                             const float* __restrict__ wpan, const float* __restrict__ w44,
                             const float* __restrict__ bias4, float* __restrict__ u,
                             int n_nodes) {
    int t = threadIdx.x;
    int node = blockIdx.x * 4 + (t >> 6);
    int c = t & 63;
    if (blockIdx.x == 0 && t < 4) u[n_nodes * 4 + t] = 0.0f;  // zero row for agg_pq4 pads
    if (node >= n_nodes) return;
    int e0 = row_start[node];
    int pd = row_pdeg[node];
    float self = bf2f(lin[(size_t)node * 64 + c]);
    float nr = norm[node];
    float a0 = 0.f, a1 = 0.f, a2 = 0.f, a3 = 0.f;
    for (int base = 0; base < pd; base += 64) {
        int sidx = csr_src[e0 + base + c];   // 64 indices, one load (over-read is benign)
        int m = min(64, pd - base);          // multiple of 16
        for (int k = 0; k < m; k += 16) {
#pragma unroll
            for (int kk = 0; kk < 16; kk += 4) {
                int s0 = __shfl(sidx, k + kk + 0);
                int s1 = __shfl(sidx, k + kk + 1);
                int s2 = __shfl(sidx, k + kk + 2);
                int s3 = __shfl(sidx, k + kk + 3);
                a0 += bf2f(lin[(size_t)s0 * 64 + c]);
                a1 += bf2f(lin[(size_t)s1 * 64 + c]);
                a2 += bf2f(lin[(size_t)s2 * 64 + c]);
                a3 += bf2f(lin[(size_t)s3 * 64 + c]);
            }
        }
    }
    float acc = (a0 + a1) + (a2 + a3);
    float w0 = wpan[0];
    float w01 = wpan[0] * wpan[1];
    float v = fmaxf(nr * (w0 * self + w01 * acc), 0.0f);   // h1[node, c]
    float4 wv = *(const float4*)(w44 + c * 4);
    float p0 = v * wv.x, p1 = v * wv.y, p2 = v * wv.z, p3 = v * wv.w;
    for (int off = 32; off; off >>= 1) {
        p0 += __shfl_xor(p0, off);
        p1 += __shfl_xor(p1, off);
        p2 += __shfl_xor(p2, off);
        p3 += __shfl_xor(p3, off);
    }
    if (c == 0) {
        float4 bb = *(const float4*)bias4;
        *(float4*)(u + node * 4) =
            make_float4(p0 + bb.x, p1 + bb.y, p2 + bb.z, p3 + bb.w);
    }
}

// Layer-2 aggregate on the rank-4 table (padded rows -> branch-free unroll 8):
// pq[n,j] = norm*(w0*u[n,j] + w01*sum u[src,j]).
__global__ void agg_pq4_kernel(const float* __restrict__ u, const int* __restrict__ row_start,
                               const int* __restrict__ row_pdeg,
                               const int* __restrict__ csr_src,
                               const float* __restrict__ norm,
                               const float* __restrict__ wpan, float* __restrict__ pq,
                               int n_nodes) {
    int t = threadIdx.x;
    int node = blockIdx.x * 64 + (t >> 2);
    int j = t & 3;
    if (node >= n_nodes) return;
    int e0 = row_start[node];
    int pd = row_pdeg[node];
    float acc = 0.0f;
    for (int e = 0; e < pd; e += 8) {
#pragma unroll
        for (int k = 0; k < 8; k++) {
            int s = csr_src[e0 + e + k];
            acc += u[s * 4 + j];
        }
    }
    float w0 = wpan[0];
    float w01 = wpan[0] * wpan[1];
    pq[node * 4 + j] = norm[node] * (w0 * u[node * 4 + j] + w01 * acc);
}

__global__ void edge_out_kernel(const int* __restrict__ src, const int* __restrict__ dst,
                                const float* __restrict__ pq, const float* __restrict__ bc,
                                float* __restrict__ out, int n_edges) {
    int e = blockIdx.x * blockDim.x + threadIdx.x;
    if (e >= n_edges) return;
    int r = src[e], c = dst[e];
    float2 p = *(const float2*)(pq + r * 4);
    float2 q = *(const float2*)(pq + c * 4 + 2);
    float2 o = make_float2(p.x + q.x + bc[0], p.y + q.y + bc[1]);
    *(float2*)(out + e * 2) = o;
}

extern "C" void kernel_launch(void* const* d_in, const int* in_sizes, int n_in,
                              void* d_out, int out_size, void* d_ws, size_t ws_size,
                              hipStream_t stream) {
    const float* x      = (const float*)d_in[0];
    const int*   eidx   = (const int*)d_in[1];
    const float* w1_lin = (const float*)d_in[2];
    const float* b1_lin = (const float*)d_in[3];
    const float* w1_pan = (const float*)d_in[4];
    const float* w2_lin = (const float*)d_in[5];
    const float* b2_lin = (const float*)d_in[6];
    const float* w2_pan = (const float*)d_in[7];
    const float* wc     = (const float*)d_in[8];
    const float* bc     = (const float*)d_in[9];
    float* out = (float*)d_out;

    const int* src = eidx;           // edge_index[0]
    const int* dst = eidx + NEDGES;  // edge_index[1]

    // ---- workspace carve-up (all 256B-aligned) ----
    char* ws = (char*)d_ws;
    size_t off = 0;
    auto carve = [&](size_t bytes) {
        char* p = ws + off;
        off = (off + bytes + 255) & ~(size_t)255;
        return p;
    };
    int*   bucket_fill = (int*)carve((size_t)NB * 4);
    int*   row_start = (int*)carve((size_t)NNODES * 4);
    int*   row_pdeg  = (int*)carve((size_t)NNODES * 4);
    unsigned int* staging = (unsigned int*)carve((size_t)NB * CAP * 4);   // 12.8 MB
    int*   csr_src  = (int*)carve((size_t)NB * CAPE * 4);                 // 19.2 MB
    float* nrm      = (float*)carve((size_t)NNODES * 4);
    unsigned short* bufA = (unsigned short*)carve((size_t)(NNODES + 1) * HIDC * 2);
    float* u        = (float*)carve((size_t)(NNODES + 1) * 4 * 4);
    float* pq       = (float*)carve((size_t)NNODES * 4 * 4);
    float* w44      = (float*)carve((size_t)64 * 4 * 4);
    float* bias4    = (float*)carve((size_t)4 * 4);
    (void)ws_size; (void)in_sizes; (void)n_in; (void)out_size;

    hipMemsetAsync(bucket_fill, 0, (size_t)NB * 4, stream);

    // fat kernel: edge binning (first 196 blocks) || layer-1 GEMM (+ w44, sentinel row)
    fat_kernel<<<NBLK_FILL + NBLK_LIN, 256, 0, stream>>>(
        x, w1_lin, b1_lin, bufA, w2_lin, b2_lin, wc, w44, bias4,
        src, dst, bucket_fill, staging);

    // CSR build pass 2: padded rows + row_start/pdeg + dedup + norm + scatter
    fill2_kernel<<<NB, 256, 0, stream>>>(bucket_fill, staging, csr_src, row_start, row_pdeg,
                                         nrm, NNODES);

    // layer 1 aggregate+relu fused with rank-4 projection -> u (1 node/wave)
    agg_h_kernel<<<(NNODES + 3) / 4, 256, 0, stream>>>(
        bufA, row_start, row_pdeg, csr_src, nrm, w1_pan, w44, bias4, u, NNODES);

    // layer 2 aggregate on the rank-4 table
    agg_pq4_kernel<<<(NNODES + 63) / 64, 256, 0, stream>>>(
        u, row_start, row_pdeg, csr_src, nrm, w2_pan, pq, NNODES);

    // edge head: out[e] = p[src[e]] + q[dst[e]] + bc
    edge_out_kernel<<<NEDGES / 256, 256, 0, stream>>>(src, dst, pq, bc, out, NEDGES);
}

// Round 12
// 254.753 us; speedup vs baseline: 1.1758x; 1.0241x over previous
//
#include <hip/hip_runtime.h>
#include <hip/hip_bf16.h>

#define NNODES 100000
#define NEDGES 1600000
#define INC 128
#define HIDC 64
#define BSHIFT 8                      // 256 nodes per bucket
#define NB ((NNODES + 255) / 256)     // 391 buckets
#define TILE 8192                     // edges per fill1 workgroup (32/thread)
#define HSLOTS 8192                   // LDS hash slots in fill2 (32 KB)
#define CAP 8192                      // staging words per bucket (avg load ~4092)
#define CAPE 8192                     // csr words per bucket (rows padded to x8)
#define NBLK_FILL ((NEDGES + TILE - 1) / TILE)   // 196
#define NBLK_LIN ((NNODES + 63) / 64)            // 1563

__device__ __forceinline__ float bf2f(unsigned short h) {
    return __uint_as_float((unsigned)h << 16);
}

// ---- fat kernel: fill1 binning (blocks [0, NBLK_FILL)) + lin1 GEMM (rest) ----
__global__ __launch_bounds__(256) void fat_kernel(
        const float* __restrict__ x, const float* __restrict__ w,
        const float* __restrict__ b, unsigned short* __restrict__ out,
        const float* __restrict__ w2_lin, const float* __restrict__ b2,
        const float* __restrict__ wc, float* __restrict__ w44,
        float* __restrict__ bias4,
        const int* __restrict__ src, const int* __restrict__ dst,
        int* __restrict__ bucket_fill, unsigned int* __restrict__ staging) {
    __shared__ float xs[64][INC + 12];   // stride 140: 2-way-free banks
    int t = threadIdx.x;
    if (blockIdx.x < NBLK_FILL) {
        // ---------------- fill1 branch ----------------
        int* cnt = (int*)&xs[0][0];
        int* basepos = cnt + NB;
        for (int i = t; i < NB; i += 256) cnt[i] = 0;
        __syncthreads();
        int tile0 = blockIdx.x * TILE;
        unsigned int sv[32];
        int meta[32];
#pragma unroll
        for (int i = 0; i < 32; i++) {
            int e = tile0 + i * 256 + t;
            meta[i] = -1;
            sv[i] = 0;
            if (e < NEDGES) {
                int s = src[e], d = dst[e];
                int bkt = d >> BSHIFT;
                int r = atomicAdd(&cnt[bkt], 1);     // < TILE = 8192 (13 bits)
                meta[i] = (bkt << 13) | r;
                sv[i] = ((unsigned)(d & 255) << 17) | (unsigned)s;
            }
        }
        __syncthreads();
        for (int i = t; i < NB; i += 256) {
            int c = cnt[i];
            int g = (c > 0) ? atomicAdd(&bucket_fill[i], c) : 0;
            basepos[i] = (i << 13) + g;              // staging region = [i*CAP, ...)
        }
        __syncthreads();
#pragma unroll
        for (int i = 0; i < 32; i++) {
            if (meta[i] >= 0) {
                int bkt = meta[i] >> 13, r = meta[i] & 8191;
                staging[basepos[bkt] + r] = sv[i];
            }
        }
    } else {
        // ---------------- lin branch ----------------
        int node0 = (blockIdx.x - NBLK_FILL) * 64;
        int nn = min(64, NNODES - node0);
        constexpr int C4 = INC / 4;
        for (int idx = t; idx < 64 * C4; idx += 256) {
            int row = idx / C4, c4 = idx % C4;
            float4 v = make_float4(0.f, 0.f, 0.f, 0.f);
            if (row < nn) v = *(const float4*)(x + (size_t)(node0 + row) * INC + c4 * 4);
            *(float4*)(&xs[row][c4 * 4]) = v;
        }
        __syncthreads();
        int tn = t >> 4, tc = t & 15;
        int n0 = tn * 4, c0 = tc * 4;
        float4 bb = *(const float4*)(b + c0);
        float acc[4][4];
#pragma unroll
        for (int i = 0; i < 4; i++) {
            acc[i][0] = bb.x; acc[i][1] = bb.y; acc[i][2] = bb.z; acc[i][3] = bb.w;
        }
        float xr[4][4], wr[4][4], xn[4][4], wn[4][4];
#pragma unroll
        for (int i = 0; i < 4; i++)
            *(float4*)&xr[i][0] = *(const float4*)(&xs[n0 + i][0]);
#pragma unroll
        for (int j = 0; j < 4; j++)
            *(float4*)&wr[j][0] = *(const float4*)(w + (size_t)j * 64 + c0);
#pragma unroll 2
        for (int k = 0; k < INC; k += 4) {
            int kn = (k + 4 < INC) ? (k + 4) : 0;    // wrap: harmless dead prefetch
#pragma unroll
            for (int i = 0; i < 4; i++)
                *(float4*)&xn[i][0] = *(const float4*)(&xs[n0 + i][kn]);
#pragma unroll
            for (int j = 0; j < 4; j++)
                *(float4*)&wn[j][0] = *(const float4*)(w + (size_t)(kn + j) * 64 + c0);
#pragma unroll
            for (int i = 0; i < 4; i++)
#pragma unroll
                for (int kk = 0; kk < 4; kk++)
#pragma unroll
                    for (int j = 0; j < 4; j++)
                        acc[i][j] += xr[i][kk] * wr[kk][j];
#pragma unroll
            for (int i = 0; i < 4; i++)
#pragma unroll
                for (int kk = 0; kk < 4; kk++) {
                    xr[i][kk] = xn[i][kk];
                    wr[i][kk] = wn[i][kk];
                }
        }
#pragma unroll
        for (int i = 0; i < 4; i++) {
            int node = node0 + n0 + i;
            if (node < NNODES) {
                __hip_bfloat16 h0 = __float2bfloat16(acc[i][0]);
                __hip_bfloat16 h1 = __float2bfloat16(acc[i][1]);
                __hip_bfloat16 h2 = __float2bfloat16(acc[i][2]);
                __hip_bfloat16 h3 = __float2bfloat16(acc[i][3]);
                ushort4 pk = make_ushort4(*(unsigned short*)&h0, *(unsigned short*)&h1,
                                          *(unsigned short*)&h2, *(unsigned short*)&h3);
                *(ushort4*)(out + (size_t)node * 64 + c0) = pk;
            }
        }
        if (blockIdx.x == NBLK_FILL) {
            if (t < 16)   // zero sentinel row for padded gathers
                *(ushort4*)(out + (size_t)NNODES * 64 + t * 4) = make_ushort4(0, 0, 0, 0);
            int k = t >> 2, j = t & 3;
            float a = 0.0f;
#pragma unroll 8
            for (int i = 0; i < 64; i++) {
                float w4 = (j < 2) ? wc[i * 2 + j] : wc[(64 + i) * 2 + (j - 2)];
                a += w2_lin[k * 64 + i] * w4;
            }
            w44[k * 4 + j] = a;
            if (k == 0) {
                float bb4 = 0.0f;
                for (int i = 0; i < 64; i++) {
                    float w4 = (j < 2) ? wc[i * 2 + j] : wc[(64 + i) * 2 + (j - 2)];
                    bb4 += b2[i] * w4;
                }
                bias4[j] = bb4;
            }
        }
    }
}

// fill pass 2: one WG per 256-node bucket, fixed csr region [b*CAPE, ...).
// Rows padded to x8 with sentinel n_nodes (points at the zero row).
__global__ __launch_bounds__(256) void fill2_kernel(
        const int* __restrict__ bucket_fill, const unsigned int* __restrict__ staging,
        int* __restrict__ csr_src, int* __restrict__ row_start,
        int* __restrict__ row_pdeg, float* __restrict__ norm, int n_nodes) {
    __shared__ int cnt[256];
    __shared__ int dcount[256];
    __shared__ int off[256];
    __shared__ int pscan[256];
    __shared__ unsigned short rank16[CAP];   // 16 KB
    __shared__ unsigned int ht[HSLOTS];      // 32 KB
    int t = threadIdx.x;
    int b = blockIdx.x;
    int node0 = b << BSHIFT;
    int nn = min(256, n_nodes - node0);
    cnt[t] = 0; dcount[t] = 0;
    {
        uint4* h4 = (uint4*)ht;
        uint4 ff = make_uint4(0xFFFFFFFFu, 0xFFFFFFFFu, 0xFFFFFFFFu, 0xFFFFFFFFu);
        for (int i = t; i < HSLOTS / 4; i += 256) h4[i] = ff;
    }
    __syncthreads();
    int start = b << 13;
    int total = bucket_fill[b];
    // phase A: count + rank + dedup
    for (int li = t; li < total; li += 256) {
        unsigned int w = staging[start + li];
        int s = (int)(w & 0x1FFFFu);
        int dl = (int)(w >> 17);
        int r = atomicAdd(&cnt[dl], 1);
        rank16[li] = (unsigned short)r;
        if (s != node0 + dl) {  // self-loops merge with the I-diagonal
            unsigned int slot = ((w * 2654435761u) >> 13) & (HSLOTS - 1);
            while (true) {
                unsigned int prev = atomicCAS(&ht[slot], 0xFFFFFFFFu, w);
                if (prev == 0xFFFFFFFFu) { atomicAdd(&dcount[dl], 1); break; }
                if (prev == w) break;
                slot = (slot + 1) & (HSLOTS - 1);
            }
        }
    }
    __syncthreads();
    // exclusive prefix of x8-padded counts -> csr offsets within [b*CAPE, ...)
    int cv = cnt[t];
    int pv = (cv + 7) & ~7;
    pscan[t] = pv;
    __syncthreads();
    for (int o = 1; o < 256; o <<= 1) {
        int xx = (t >= o) ? pscan[t - o] : 0;
        __syncthreads();
        pscan[t] += xx;
        __syncthreads();
    }
    off[t] = b * CAPE + pscan[t] - pv;
    __syncthreads();
    if (t < nn) {
        row_start[node0 + t] = off[t];
        row_pdeg[node0 + t] = pv;
        norm[node0 + t] = 1.0f / (1.0f + (float)dcount[t]);
    }
    // sentinel-pad the tail of each row
    for (int k = cv; k < pv; k++) csr_src[off[t] + k] = n_nodes;
    // phase B: scatter csr
    for (int li = t; li < total; li += 256) {
        unsigned int w = staging[start + li];
        int s = (int)(w & 0x1FFFFu);
        int dl = (int)(w >> 17);
        csr_src[off[dl] + (int)rank16[li]] = s;
    }
}

// One wave per node; edge-paired dword gathers: lanes 0-31 process edge 2p
// (2 bf16 channels/lane), lanes 32-63 edge 2p+1. Pair indices via readlane
// (SGPR, uniform). Halves combined with one shfl_xor(32). Fused PAN combine +
// relu + rank-4 projection -> u. h1 never hits global memory.
__global__ void agg_h_kernel(const unsigned int* __restrict__ lin32,
                             const int* __restrict__ row_start,
                             const int* __restrict__ row_pdeg,
                             const int* __restrict__ csr_src,
                             const float* __restrict__ norm,
                             const float* __restrict__ wpan, const float* __restrict__ w44,
                             const float* __restrict__ bias4, float* __restrict__ u,
                             int n_nodes) {
    int t = threadIdx.x;
    int node = blockIdx.x * 4 + (t >> 6);
    int lane = t & 63;
    int sl = lane & 31;
    int h5 = lane >> 5;
    if (blockIdx.x == 0 && t < 4) u[n_nodes * 4 + t] = 0.0f;  // zero row for agg_pq4 pads
    if (node >= n_nodes) return;
    int e0 = row_start[node];
    int pd = row_pdeg[node];                 // multiple of 8
    float aLo0 = 0.f, aHi0 = 0.f, aLo1 = 0.f, aHi1 = 0.f;
    for (int base = 0; base < pd; base += 64) {
        int sidx = csr_src[e0 + base + lane];   // 64 indices, one load (slack-guarded)
        int m = min(64, pd - base);             // multiple of 8
        for (int p = 0; p < m; p += 8) {        // 8 edges = 4 paired loads
#pragma unroll
            for (int pp = 0; pp < 8; pp += 4) {
                int sA0 = __builtin_amdgcn_readlane(sidx, p + pp + 0);
                int sB0 = __builtin_amdgcn_readlane(sidx, p + pp + 1);
                int sA1 = __builtin_amdgcn_readlane(sidx, p + pp + 2);
                int sB1 = __builtin_amdgcn_readlane(sidx, p + pp + 3);
                int s0 = h5 ? sB0 : sA0;
                int s1 = h5 ? sB1 : sA1;
                unsigned int wd0 = lin32[(size_t)s0 * 32 + sl];
                unsigned int wd1 = lin32[(size_t)s1 * 32 + sl];
                aLo0 += __uint_as_float(wd0 << 16);
                aHi0 += __uint_as_float(wd0 & 0xFFFF0000u);
                aLo1 += __uint_as_float(wd1 << 16);
                aHi1 += __uint_as_float(wd1 & 0xFFFF0000u);
            }
        }
    }
    float accLo = aLo0 + aLo1;
    float accHi = aHi0 + aHi1;
    accLo += __shfl_xor(accLo, 32);          // combine even/odd edge halves
    accHi += __shfl_xor(accHi, 32);
    unsigned int wself = lin32[(size_t)node * 32 + sl];
    float nr = norm[node];
    float w0 = wpan[0];
    float w01 = wpan[0] * wpan[1];
    float vLo = fmaxf(nr * (w0 * __uint_as_float(wself << 16) + w01 * accLo), 0.0f);
    float vHi = fmaxf(nr * (w0 * __uint_as_float(wself & 0xFFFF0000u) + w01 * accHi), 0.0f);
    int c0 = 2 * sl;
    float4 wv0 = *(const float4*)(w44 + c0 * 4);
    float4 wv1 = *(const float4*)(w44 + (c0 + 1) * 4);
    float p0 = vLo * wv0.x + vHi * wv1.x;
    float p1 = vLo * wv0.y + vHi * wv1.y;
    float p2 = vLo * wv0.z + vHi * wv1.z;
    float p3 = vLo * wv0.w + vHi * wv1.w;
    for (int off = 16; off; off >>= 1) {     // reduce over 32 lanes (halves identical)
        p0 += __shfl_xor(p0, off);
        p1 += __shfl_xor(p1, off);
        p2 += __shfl_xor(p2, off);
        p3 += __shfl_xor(p3, off);
    }
    if (lane == 0) {
        float4 bb = *(const float4*)bias4;
        *(float4*)(u + node * 4) =
            make_float4(p0 + bb.x, p1 + bb.y, p2 + bb.z, p3 + bb.w);
    }
}

// Layer-2 aggregate on the rank-4 table (x8-padded rows, branch-free):
// pq[n,j] = norm*(w0*u[n,j] + w01*sum u[src,j]).
__global__ void agg_pq4_kernel(const float* __restrict__ u, const int* __restrict__ row_start,
                               const int* __restrict__ row_pdeg,
                               const int* __restrict__ csr_src,
                               const float* __restrict__ norm,
                               const float* __restrict__ wpan, float* __restrict__ pq,
                               int n_nodes) {
    int t = threadIdx.x;
    int node = blockIdx.x * 64 + (t >> 2);
    int j = t & 3;
    if (node >= n_nodes) return;
    int e0 = row_start[node];
    int pd = row_pdeg[node];
    float acc = 0.0f;
    for (int e = 0; e < pd; e += 8) {
#pragma unroll
        for (int k = 0; k < 8; k++) {
            int s = csr_src[e0 + e + k];
            acc += u[s * 4 + j];
        }
    }
    float w0 = wpan[0];
    float w01 = wpan[0] * wpan[1];
    pq[node * 4 + j] = norm[node] * (w0 * u[node * 4 + j] + w01 * acc);
}

__global__ void edge_out_kernel(const int* __restrict__ src, const int* __restrict__ dst,
                                const float* __restrict__ pq, const float* __restrict__ bc,
                                float* __restrict__ out, int n_edges) {
    int e = blockIdx.x * blockDim.x + threadIdx.x;
    if (e >= n_edges) return;
    int r = src[e], c = dst[e];
    float2 p = *(const float2*)(pq + r * 4);
    float2 q = *(const float2*)(pq + c * 4 + 2);
    float2 o = make_float2(p.x + q.x + bc[0], p.y + q.y + bc[1]);
    *(float2*)(out + e * 2) = o;
}

extern "C" void kernel_launch(void* const* d_in, const int* in_sizes, int n_in,
                              void* d_out, int out_size, void* d_ws, size_t ws_size,
                              hipStream_t stream) {
    const float* x      = (const float*)d_in[0];
    const int*   eidx   = (const int*)d_in[1];
    const float* w1_lin = (const float*)d_in[2];
    const float* b1_lin = (const float*)d_in[3];
    const float* w1_pan = (const float*)d_in[4];
    const float* w2_lin = (const float*)d_in[5];
    const float* b2_lin = (const float*)d_in[6];
    const float* w2_pan = (const float*)d_in[7];
    const float* wc     = (const float*)d_in[8];
    const float* bc     = (const float*)d_in[9];
    float* out = (float*)d_out;

    const int* src = eidx;           // edge_index[0]
    const int* dst = eidx + NEDGES;  // edge_index[1]

    // ---- workspace carve-up (all 256B-aligned) ----
    char* ws = (char*)d_ws;
    size_t off = 0;
    auto carve = [&](size_t bytes) {
        char* p = ws + off;
        off = (off + bytes + 255) & ~(size_t)255;
        return p;
    };
    int*   bucket_fill = (int*)carve((size_t)NB * 4);
    int*   row_start = (int*)carve((size_t)NNODES * 4);
    int*   row_pdeg  = (int*)carve((size_t)NNODES * 4);
    unsigned int* staging = (unsigned int*)carve((size_t)NB * CAP * 4);   // 12.8 MB
    int*   csr_src  = (int*)carve(((size_t)NB * CAPE + 256) * 4);         // 12.8 MB + slack
    float* nrm      = (float*)carve((size_t)NNODES * 4);
    unsigned short* bufA = (unsigned short*)carve((size_t)(NNODES + 1) * HIDC * 2);
    float* u        = (float*)carve((size_t)(NNODES + 1) * 4 * 4);
    float* pq       = (float*)carve((size_t)NNODES * 4 * 4);
    float* w44      = (float*)carve((size_t)64 * 4 * 4);
    float* bias4    = (float*)carve((size_t)4 * 4);
    (void)ws_size; (void)in_sizes; (void)n_in; (void)out_size;

    hipMemsetAsync(bucket_fill, 0, (size_t)NB * 4, stream);

    // fat kernel: edge binning (first 196 blocks) || layer-1 GEMM (+ w44, sentinel row)
    fat_kernel<<<NBLK_FILL + NBLK_LIN, 256, 0, stream>>>(
        x, w1_lin, b1_lin, bufA, w2_lin, b2_lin, wc, w44, bias4,
        src, dst, bucket_fill, staging);

    // CSR build pass 2: x8-padded rows + row_start/pdeg + dedup + norm + scatter
    fill2_kernel<<<NB, 256, 0, stream>>>(bucket_fill, staging, csr_src, row_start, row_pdeg,
                                         nrm, NNODES);

    // layer 1 aggregate+relu fused with rank-4 projection -> u (1 node/wave, paired gathers)
    agg_h_kernel<<<(NNODES + 3) / 4, 256, 0, stream>>>(
        (const unsigned int*)bufA, row_start, row_pdeg, csr_src, nrm, w1_pan, w44, bias4,
        u, NNODES);

    // layer 2 aggregate on the rank-4 table
    agg_pq4_kernel<<<(NNODES + 63) / 64, 256, 0, stream>>>(
        u, row_start, row_pdeg, csr_src, nrm, w2_pan, pq, NNODES);

    // edge head: out[e] = p[src[e]] + q[dst[e]] + bc
    edge_out_kernel<<<NEDGES / 256, 256, 0, stream>>>(src, dst, pq, bc, out, NEDGES);
}